// Round 1
// baseline (206.901 us; speedup 1.0000x reference)
//
#include <hip/hip_runtime.h>

#define NB 32
#define NM 128
#define NL 32
#define NH 512
#define NV 32000
#define NHOPS 3
#define NEG_INF -1e9f

// ---------------------------------------------------------------------------
// Pool kernel: one block per (b,m); pools NT consecutive tables at once.
// P[t][bm][h] = sum_l C[t][inputs[bm][l]][h]
// 128 threads, each owns 4 consecutive h (float4) -> full 2KB row coalesced.
// ---------------------------------------------------------------------------
template <int NT>
__global__ __launch_bounds__(128)
void pool_kernel(const int* __restrict__ inputs,
                 const float* __restrict__ Ctab,   // base of first table
                 float* __restrict__ P) {          // [NT][NB*NM][NH] contiguous
    const int bm  = blockIdx.x;
    const int tid = threadIdx.x;
    __shared__ int idx[NL];
    if (tid < NL) idx[tid] = inputs[bm * NL + tid];
    __syncthreads();

    const int hoff = tid * 4;
    float4 acc[NT];
#pragma unroll
    for (int t = 0; t < NT; ++t) acc[t] = make_float4(0.f, 0.f, 0.f, 0.f);

    for (int l = 0; l < NL; ++l) {
        const size_t rowbase = (size_t)idx[l] * NH + hoff;
#pragma unroll
        for (int t = 0; t < NT; ++t) {
            const float4 v = *reinterpret_cast<const float4*>(
                Ctab + (size_t)t * NV * NH + rowbase);
            acc[t].x += v.x; acc[t].y += v.y; acc[t].z += v.z; acc[t].w += v.w;
        }
    }
#pragma unroll
    for (int t = 0; t < NT; ++t) {
        *reinterpret_cast<float4*>(
            P + ((size_t)t * NB * NM + bm) * NH + hoff) = acc[t];
    }
}

// ---------------------------------------------------------------------------
// Hop kernel: one block per batch b, 512 threads (8 waves).
//   scores[m] = u . PA[b,m,:]      (wave-per-row, shuffle reduce)
//   attn     = softmax(mask ? -1e9 : scores)
//   u_out    = u + sum_m attn[m] * PC[b,m,:]
// ---------------------------------------------------------------------------
__global__ __launch_bounds__(512)
void hop_kernel(const float* __restrict__ u_in,    // [NB,NH]
                const float* __restrict__ PA,      // [NB*NM,NH]
                const float* __restrict__ PC,      // [NB*NM,NH]
                const int*   __restrict__ lengths, // [NB,NM]
                float* __restrict__ u_out,         // [NB,NH]
                float* __restrict__ attn_out) {    // [NB,NM]
    const int b   = blockIdx.x;
    const int tid = threadIdx.x;
    __shared__ float u_s[NH];
    __shared__ float sc[NM];
    __shared__ float tmp[512];

    u_s[tid] = u_in[b * NH + tid];
    __syncthreads();

    const int wave = tid >> 6;
    const int lane = tid & 63;
    for (int m = wave; m < NM; m += 8) {
        const float* row = PA + ((size_t)b * NM + m) * NH;
        float p = 0.f;
#pragma unroll
        for (int k = 0; k < NH / 64; ++k) {
            const int h = lane + k * 64;
            p += u_s[h] * row[h];
        }
#pragma unroll
        for (int off = 32; off; off >>= 1) p += __shfl_down(p, off, 64);
        if (lane == 0) sc[m] = p;
    }
    __syncthreads();

    // masked softmax over NM (tree reduce across 512 threads)
    float s = NEG_INF;
    if (tid < NM) s = (lengths[b * NM + tid] == 0) ? NEG_INF : sc[tid];
    tmp[tid] = s;
    __syncthreads();
    for (int st = 256; st >= 1; st >>= 1) {
        if (tid < st) tmp[tid] = fmaxf(tmp[tid], tmp[tid + st]);
        __syncthreads();
    }
    const float mx = tmp[0];
    __syncthreads();
    const float e = (tid < NM) ? expf(s - mx) : 0.f;
    tmp[tid] = e;
    __syncthreads();
    for (int st = 256; st >= 1; st >>= 1) {
        if (tid < st) tmp[tid] += tmp[tid + st];
        __syncthreads();
    }
    const float inv = 1.f / tmp[0];
    __syncthreads();
    if (tid < NM) {
        const float a = e * inv;
        sc[tid] = a;
        attn_out[b * NM + tid] = a;
    }
    __syncthreads();

    // u update: each thread owns one h
    float acc = 0.f;
    for (int m = 0; m < NM; ++m) {
        acc += sc[m] * PC[((size_t)b * NM + m) * NH + tid];
    }
    u_out[b * NH + tid] = u_s[tid] + acc;
}

// ---------------------------------------------------------------------------
// Fallback path (tiny workspace): gather on the fly per hop.
// ---------------------------------------------------------------------------
__global__ __launch_bounds__(128)
void scores_gather_kernel(const int* __restrict__ inputs,
                          const float* __restrict__ Ctab,   // C[h]
                          const float* __restrict__ u_in,
                          const int*   __restrict__ lengths,
                          float* __restrict__ scores) {     // [NB*NM]
    const int bm  = blockIdx.x;
    const int b   = bm / NM;
    const int tid = threadIdx.x;
    __shared__ int idx[NL];
    if (tid < NL) idx[tid] = inputs[bm * NL + tid];
    __syncthreads();
    const int hoff = tid * 4;
    const float4 u4 = *reinterpret_cast<const float4*>(u_in + b * NH + hoff);
    float p = 0.f;
    for (int l = 0; l < NL; ++l) {
        const float4 v = *reinterpret_cast<const float4*>(
            Ctab + (size_t)idx[l] * NH + hoff);
        p += u4.x * v.x + u4.y * v.y + u4.z * v.z + u4.w * v.w;
    }
#pragma unroll
    for (int off = 32; off; off >>= 1) p += __shfl_down(p, off, 64);
    __shared__ float w2[2];
    if ((tid & 63) == 0) w2[tid >> 6] = p;
    __syncthreads();
    if (tid == 0) {
        float sres = w2[0] + w2[1];
        if (lengths[bm] == 0) sres = NEG_INF;
        scores[bm] = sres;
    }
}

__global__ __launch_bounds__(128)
void softmax_kernel(const float* __restrict__ scores,
                    float* __restrict__ attn_ws,
                    float* __restrict__ attn_out) {
    const int b   = blockIdx.x;
    const int tid = threadIdx.x;
    const float s = scores[b * NM + tid];
    float p = s;
#pragma unroll
    for (int off = 32; off; off >>= 1) p = fmaxf(p, __shfl_down(p, off, 64));
    __shared__ float w2[2];
    if ((tid & 63) == 0) w2[tid >> 6] = p;
    __syncthreads();
    const float mx = fmaxf(w2[0], w2[1]);
    const float e = expf(s - mx);
    float q = e;
#pragma unroll
    for (int off = 32; off; off >>= 1) q += __shfl_down(q, off, 64);
    __shared__ float w3[2];
    if ((tid & 63) == 0) w3[tid >> 6] = q;
    __syncthreads();
    const float a = e / (w3[0] + w3[1]);
    attn_ws[b * NM + tid]  = a;
    attn_out[b * NM + tid] = a;
}

__global__ __launch_bounds__(512)
void update_gather_kernel(const int* __restrict__ inputs,
                          const float* __restrict__ Ctab,   // C[h+1]
                          const float* __restrict__ u_in,
                          const float* __restrict__ attn,
                          float* __restrict__ u_out) {
    const int b   = blockIdx.x;
    const int tid = threadIdx.x;
    __shared__ float a_s[NM];
    __shared__ int   idx_s[NM * NL];
    if (tid < NM) a_s[tid] = attn[b * NM + tid];
    for (int i = tid; i < NM * NL; i += 512) idx_s[i] = inputs[b * NM * NL + i];
    __syncthreads();
    float acc = u_in[b * NH + tid];
    for (int m = 0; m < NM; ++m) {
        const float a = a_s[m];
        float part = 0.f;
        for (int l = 0; l < NL; ++l) {
            part += Ctab[(size_t)idx_s[m * NL + l] * NH + tid];
        }
        acc += a * part;
    }
    u_out[b * NH + tid] = acc;
}

// ---------------------------------------------------------------------------
extern "C" void kernel_launch(void* const* d_in, const int* in_sizes, int n_in,
                              void* d_out, int out_size, void* d_ws, size_t ws_size,
                              hipStream_t stream) {
    const int*   inputs  = (const int*)d_in[0];
    const int*   lengths = (const int*)d_in[1];
    const float* enc     = (const float*)d_in[2];
    const float* C       = (const float*)d_in[3];

    float* out     = (float*)d_out;
    float* u_final = out;                 // [NB*NH]
    float* attns   = out + NB * NH;       // [NHOPS*NB*NM]

    const size_t POOL_ELEMS = (size_t)NB * NM * NH;   // one table pool
    const size_t U_ELEMS    = (size_t)NB * NH;
    float* ws = (float*)d_ws;

    if (ws_size >= (4 * POOL_ELEMS + 2 * U_ELEMS) * sizeof(float)) {
        // Primary: all 4 pools in one parallel kernel, then 3 tiny hop kernels.
        float* P  = ws;
        float* u1 = ws + 4 * POOL_ELEMS;
        float* u2 = u1 + U_ELEMS;
        pool_kernel<4><<<NB * NM, 128, 0, stream>>>(inputs, C, P);
        const float* uin[NHOPS] = {enc, u1, u2};
        float*       uou[NHOPS] = {u1, u2, u_final};
        for (int h = 0; h < NHOPS; ++h) {
            hop_kernel<<<NB, 512, 0, stream>>>(
                uin[h], P + (size_t)h * POOL_ELEMS, P + (size_t)(h + 1) * POOL_ELEMS,
                lengths, uou[h], attns + (size_t)h * NB * NM);
        }
    } else if (ws_size >= (2 * POOL_ELEMS + 2 * U_ELEMS) * sizeof(float)) {
        // Two pool buffers, interleave pool/hop.
        float* P0 = ws;
        float* P1 = ws + POOL_ELEMS;
        float* u1 = ws + 2 * POOL_ELEMS;
        float* u2 = u1 + U_ELEMS;
        pool_kernel<2><<<NB * NM, 128, 0, stream>>>(inputs, C, P0);            // P0,P1
        hop_kernel<<<NB, 512, 0, stream>>>(enc, P0, P1, lengths, u1, attns);
        pool_kernel<1><<<NB * NM, 128, 0, stream>>>(inputs, C + 2 * (size_t)NV * NH, P0);
        hop_kernel<<<NB, 512, 0, stream>>>(u1, P1, P0, lengths, u2, attns + NB * NM);
        pool_kernel<1><<<NB * NM, 128, 0, stream>>>(inputs, C + 3 * (size_t)NV * NH, P1);
        hop_kernel<<<NB, 512, 0, stream>>>(u2, P0, P1, lengths, u_final, attns + 2 * NB * NM);
    } else {
        // Tiny-workspace fallback: gather on the fly per hop.
        float* scores  = ws;                      // [NB*NM]
        float* attn_ws = ws + NB * NM;            // [NB*NM]
        float* u1      = attn_ws + NB * NM;
        float* u2      = u1 + U_ELEMS;
        const float* uin = enc;
        float* uou[NHOPS] = {u1, u2, u_final};
        for (int h = 0; h < NHOPS; ++h) {
            scores_gather_kernel<<<NB * NM, 128, 0, stream>>>(
                inputs, C + (size_t)h * NV * NH, uin, lengths, scores);
            softmax_kernel<<<NB, 128, 0, stream>>>(
                scores, attn_ws, attns + (size_t)h * NB * NM);
            update_gather_kernel<<<NB, 512, 0, stream>>>(
                inputs, C + (size_t)(h + 1) * NV * NH, uin, attn_ws, uou[h]);
            uin = uou[h];
        }
    }
}

// Round 2
// 203.067 us; speedup vs baseline: 1.0189x; 1.0189x over previous
//
#include <hip/hip_runtime.h>

#define NB 32
#define NM 128
#define NL 32
#define NH 512
#define NV 32000
#define NHOPS 3
#define NEG_INF -1e9f

// ---------------------------------------------------------------------------
// Pool kernel: one block per (b,m); pools NT consecutive tables at once.
// P[t][bm][h] = sum_l C[t][inputs[bm][l]][h]
// 128 threads, each owns 4 consecutive h (float4) -> full 2KB row coalesced.
// NT=2 keeps per-pass working set (2 tables = 131MB + 67MB P writes) < 256MB L3.
// ---------------------------------------------------------------------------
template <int NT>
__global__ __launch_bounds__(128)
void pool_kernel(const int* __restrict__ inputs,
                 const float* __restrict__ Ctab,   // base of first table
                 float* __restrict__ P) {          // [NT][NB*NM][NH] contiguous
    const int bm  = blockIdx.x;
    const int tid = threadIdx.x;
    __shared__ int idx[NL];
    if (tid < NL) idx[tid] = inputs[bm * NL + tid];
    __syncthreads();

    const int hoff = tid * 4;
    float4 acc[NT];
#pragma unroll
    for (int t = 0; t < NT; ++t) acc[t] = make_float4(0.f, 0.f, 0.f, 0.f);

#pragma unroll 8
    for (int l = 0; l < NL; ++l) {
        const size_t rowbase = (size_t)idx[l] * NH + hoff;
#pragma unroll
        for (int t = 0; t < NT; ++t) {
            const float4 v = *reinterpret_cast<const float4*>(
                Ctab + (size_t)t * NV * NH + rowbase);
            acc[t].x += v.x; acc[t].y += v.y; acc[t].z += v.z; acc[t].w += v.w;
        }
    }
#pragma unroll
    for (int t = 0; t < NT; ++t) {
        *reinterpret_cast<float4*>(
            P + ((size_t)t * NB * NM + bm) * NH + hoff) = acc[t];
    }
}

// ---------------------------------------------------------------------------
// Hop kernel: one block per batch b, 512 threads (8 waves).
//   scores[m] = u . PA[b,m,:]      (wave-per-row, shuffle reduce)
//   attn     = softmax(mask ? -1e9 : scores)
//   u_out    = u + sum_m attn[m] * PC[b,m,:]
// ---------------------------------------------------------------------------
__global__ __launch_bounds__(512)
void hop_kernel(const float* __restrict__ u_in,    // [NB,NH]
                const float* __restrict__ PA,      // [NB*NM,NH]
                const float* __restrict__ PC,      // [NB*NM,NH]
                const int*   __restrict__ lengths, // [NB,NM]
                float* __restrict__ u_out,         // [NB,NH]
                float* __restrict__ attn_out) {    // [NB,NM]
    const int b   = blockIdx.x;
    const int tid = threadIdx.x;
    __shared__ float u_s[NH];
    __shared__ float sc[NM];
    __shared__ float tmp[512];

    u_s[tid] = u_in[b * NH + tid];
    __syncthreads();

    const int wave = tid >> 6;
    const int lane = tid & 63;
    for (int m = wave; m < NM; m += 8) {
        const float* row = PA + ((size_t)b * NM + m) * NH;
        float p = 0.f;
#pragma unroll
        for (int k = 0; k < NH / 64; ++k) {
            const int h = lane + k * 64;
            p += u_s[h] * row[h];
        }
#pragma unroll
        for (int off = 32; off; off >>= 1) p += __shfl_down(p, off, 64);
        if (lane == 0) sc[m] = p;
    }
    __syncthreads();

    // masked softmax over NM (tree reduce across 512 threads)
    float s = NEG_INF;
    if (tid < NM) s = (lengths[b * NM + tid] == 0) ? NEG_INF : sc[tid];
    tmp[tid] = s;
    __syncthreads();
    for (int st = 256; st >= 1; st >>= 1) {
        if (tid < st) tmp[tid] = fmaxf(tmp[tid], tmp[tid + st]);
        __syncthreads();
    }
    const float mx = tmp[0];
    __syncthreads();
    const float e = (tid < NM) ? expf(s - mx) : 0.f;
    tmp[tid] = e;
    __syncthreads();
    for (int st = 256; st >= 1; st >>= 1) {
        if (tid < st) tmp[tid] += tmp[tid + st];
        __syncthreads();
    }
    const float inv = 1.f / tmp[0];
    __syncthreads();
    if (tid < NM) {
        const float a = e * inv;
        sc[tid] = a;
        attn_out[b * NM + tid] = a;
    }
    __syncthreads();

    // u update: each thread owns one h
    float acc = 0.f;
    for (int m = 0; m < NM; ++m) {
        acc += sc[m] * PC[((size_t)b * NM + m) * NH + tid];
    }
    u_out[b * NH + tid] = u_s[tid] + acc;
}

// ---------------------------------------------------------------------------
// Fallback path (tiny workspace): gather on the fly per hop.
// ---------------------------------------------------------------------------
__global__ __launch_bounds__(128)
void scores_gather_kernel(const int* __restrict__ inputs,
                          const float* __restrict__ Ctab,   // C[h]
                          const float* __restrict__ u_in,
                          const int*   __restrict__ lengths,
                          float* __restrict__ scores) {     // [NB*NM]
    const int bm  = blockIdx.x;
    const int b   = bm / NM;
    const int tid = threadIdx.x;
    __shared__ int idx[NL];
    if (tid < NL) idx[tid] = inputs[bm * NL + tid];
    __syncthreads();
    const int hoff = tid * 4;
    const float4 u4 = *reinterpret_cast<const float4*>(u_in + b * NH + hoff);
    float p = 0.f;
    for (int l = 0; l < NL; ++l) {
        const float4 v = *reinterpret_cast<const float4*>(
            Ctab + (size_t)idx[l] * NH + hoff);
        p += u4.x * v.x + u4.y * v.y + u4.z * v.z + u4.w * v.w;
    }
#pragma unroll
    for (int off = 32; off; off >>= 1) p += __shfl_down(p, off, 64);
    __shared__ float w2[2];
    if ((tid & 63) == 0) w2[tid >> 6] = p;
    __syncthreads();
    if (tid == 0) {
        float sres = w2[0] + w2[1];
        if (lengths[bm] == 0) sres = NEG_INF;
        scores[bm] = sres;
    }
}

__global__ __launch_bounds__(128)
void softmax_kernel(const float* __restrict__ scores,
                    float* __restrict__ attn_ws,
                    float* __restrict__ attn_out) {
    const int b   = blockIdx.x;
    const int tid = threadIdx.x;
    const float s = scores[b * NM + tid];
    float p = s;
#pragma unroll
    for (int off = 32; off; off >>= 1) p = fmaxf(p, __shfl_down(p, off, 64));
    __shared__ float w2[2];
    if ((tid & 63) == 0) w2[tid >> 6] = p;
    __syncthreads();
    const float mx = fmaxf(w2[0], w2[1]);
    const float e = expf(s - mx);
    float q = e;
#pragma unroll
    for (int off = 32; off; off >>= 1) q += __shfl_down(q, off, 64);
    __shared__ float w3[2];
    if ((tid & 63) == 0) w3[tid >> 6] = q;
    __syncthreads();
    const float a = e / (w3[0] + w3[1]);
    attn_ws[b * NM + tid]  = a;
    attn_out[b * NM + tid] = a;
}

__global__ __launch_bounds__(512)
void update_gather_kernel(const int* __restrict__ inputs,
                          const float* __restrict__ Ctab,   // C[h+1]
                          const float* __restrict__ u_in,
                          const float* __restrict__ attn,
                          float* __restrict__ u_out) {
    const int b   = blockIdx.x;
    const int tid = threadIdx.x;
    __shared__ float a_s[NM];
    __shared__ int   idx_s[NM * NL];
    if (tid < NM) a_s[tid] = attn[b * NM + tid];
    for (int i = tid; i < NM * NL; i += 512) idx_s[i] = inputs[b * NM * NL + i];
    __syncthreads();
    float acc = u_in[b * NH + tid];
    for (int m = 0; m < NM; ++m) {
        const float a = a_s[m];
        float part = 0.f;
        for (int l = 0; l < NL; ++l) {
            part += Ctab[(size_t)idx_s[m * NL + l] * NH + tid];
        }
        acc += a * part;
    }
    u_out[b * NH + tid] = acc;
}

// ---------------------------------------------------------------------------
extern "C" void kernel_launch(void* const* d_in, const int* in_sizes, int n_in,
                              void* d_out, int out_size, void* d_ws, size_t ws_size,
                              hipStream_t stream) {
    const int*   inputs  = (const int*)d_in[0];
    const int*   lengths = (const int*)d_in[1];
    const float* enc     = (const float*)d_in[2];
    const float* C       = (const float*)d_in[3];

    float* out     = (float*)d_out;
    float* u_final = out;                 // [NB*NH]
    float* attns   = out + NB * NH;       // [NHOPS*NB*NM]

    const size_t POOL_ELEMS = (size_t)NB * NM * NH;   // one table pool
    const size_t U_ELEMS    = (size_t)NB * NH;
    const size_t TAB_ELEMS  = (size_t)NV * NH;
    float* ws = (float*)d_ws;

    if (ws_size >= (4 * POOL_ELEMS + 2 * U_ELEMS) * sizeof(float)) {
        // Primary: two NT=2 pool passes (each working set ~198MB < 256MB L3),
        // hop0 interleaved so it reads P0/P1 while L3-hot.
        float* P  = ws;
        float* u1 = ws + 4 * POOL_ELEMS;
        float* u2 = u1 + U_ELEMS;
        pool_kernel<2><<<NB * NM, 128, 0, stream>>>(inputs, C, P);   // P0, P1
        hop_kernel<<<NB, 512, 0, stream>>>(
            enc, P, P + POOL_ELEMS, lengths, u1, attns);
        pool_kernel<2><<<NB * NM, 128, 0, stream>>>(
            inputs, C + 2 * TAB_ELEMS, P + 2 * POOL_ELEMS);          // P2, P3
        hop_kernel<<<NB, 512, 0, stream>>>(
            u1, P + POOL_ELEMS, P + 2 * POOL_ELEMS, lengths, u2, attns + NB * NM);
        hop_kernel<<<NB, 512, 0, stream>>>(
            u2, P + 2 * POOL_ELEMS, P + 3 * POOL_ELEMS, lengths, u_final,
            attns + 2 * NB * NM);
    } else if (ws_size >= (2 * POOL_ELEMS + 2 * U_ELEMS) * sizeof(float)) {
        // Two pool buffers, interleave pool/hop.
        float* P0 = ws;
        float* P1 = ws + POOL_ELEMS;
        float* u1 = ws + 2 * POOL_ELEMS;
        float* u2 = u1 + U_ELEMS;
        pool_kernel<2><<<NB * NM, 128, 0, stream>>>(inputs, C, P0);            // P0,P1
        hop_kernel<<<NB, 512, 0, stream>>>(enc, P0, P1, lengths, u1, attns);
        pool_kernel<1><<<NB * NM, 128, 0, stream>>>(inputs, C + 2 * TAB_ELEMS, P0);
        hop_kernel<<<NB, 512, 0, stream>>>(u1, P1, P0, lengths, u2, attns + NB * NM);
        pool_kernel<1><<<NB * NM, 128, 0, stream>>>(inputs, C + 3 * TAB_ELEMS, P1);
        hop_kernel<<<NB, 512, 0, stream>>>(u2, P0, P1, lengths, u_final, attns + 2 * NB * NM);
    } else {
        // Tiny-workspace fallback: gather on the fly per hop.
        float* scores  = ws;                      // [NB*NM]
        float* attn_ws = ws + NB * NM;            // [NB*NM]
        float* u1      = attn_ws + NB * NM;
        float* u2      = u1 + U_ELEMS;
        const float* uin = enc;
        float* uou[NHOPS] = {u1, u2, u_final};
        for (int h = 0; h < NHOPS; ++h) {
            scores_gather_kernel<<<NB * NM, 128, 0, stream>>>(
                inputs, C + (size_t)h * TAB_ELEMS, uin, lengths, scores);
            softmax_kernel<<<NB, 128, 0, stream>>>(
                scores, attn_ws, attns + (size_t)h * NB * NM);
            update_gather_kernel<<<NB, 512, 0, stream>>>(
                inputs, C + (size_t)(h + 1) * TAB_ELEMS, uin, attn_ws, uou[h]);
            uin = uou[h];
        }
    }
}